// Round 1
// baseline (132.026 us; speedup 1.0000x reference)
//
#include <hip/hip_runtime.h>
#include <hip/hip_bf16.h>
#include <cstdint>

// Problem dims (fixed by reference)
constexpr int B  = 8;
constexpr int LQ = 256;
constexpr int LK = 256;
constexpr int D  = 512;   // Dq == Dk
constexpr int A  = 256;

constexpr float NEG_INF = -1e15f;          // matches reference INFINITY constant
constexpr float LOG2E   = 1.4426950408889634f;
constexpr float TWO_LOG2E = 2.8853900817779268f;

// ---------------- transpose W [A][D] -> WT [D][A] ----------------
__global__ __launch_bounds__(256) void transpose_w(const float* __restrict__ in,
                                                   float* __restrict__ out) {
    __shared__ float tile[32][33];
    int tx = threadIdx.x;           // 0..31
    int ty = threadIdx.y;           // 0..7
    int d0 = blockIdx.x * 32;       // along D (16 tiles)
    int a0 = blockIdx.y * 32;       // along A (8 tiles)
#pragma unroll
    for (int j = 0; j < 32; j += 8)
        tile[ty + j][tx] = in[(a0 + ty + j) * D + d0 + tx];
    __syncthreads();
#pragma unroll
    for (int j = 0; j < 32; j += 8)
        out[(d0 + ty + j) * A + a0 + tx] = tile[tx][ty + j];
}

// ---------------- projection: rows of X [nrows][D] * WT [D][A] ----------------
// thread t = a index; TL rows per block.
// transpose_out==0: out[row][a]   (for q_proj, [B*LQ][A])
// transpose_out==1: out[b][a][k]  (for k_proj, [B][A][LK])
template <int TL>
__global__ __launch_bounds__(256) void proj_kernel(const float* __restrict__ X,
                                                   const float* __restrict__ WT,
                                                   float* __restrict__ out,
                                                   int transpose_out) {
    const int t  = threadIdx.x;         // a
    const int r0 = blockIdx.x * TL;     // first row
    const float* xb = X + (size_t)r0 * D;

    float acc[TL];
#pragma unroll
    for (int j = 0; j < TL; ++j) acc[j] = 0.f;

#pragma unroll 4
    for (int d = 0; d < D; ++d) {
        float w = WT[d * A + t];        // coalesced vector load
#pragma unroll
        for (int j = 0; j < TL; ++j)
            acc[j] = fmaf(xb[j * D + d], w, acc[j]);  // xb[...] wave-uniform -> s_load
    }

    if (!transpose_out) {
#pragma unroll
        for (int j = 0; j < TL; ++j)
            out[(size_t)(r0 + j) * A + t] = acc[j];
    } else {
#pragma unroll
        for (int j = 0; j < TL; ++j) {
            int row = r0 + j;
            int bb  = row >> 8;         // 256 k-rows per batch
            int kk  = row & 255;
            out[(size_t)bb * A * LK + (size_t)t * LK + kk] = acc[j];
        }
    }
}

// ---------------- fused score + mask + softmax ----------------
// block: TL q-rows (same b), 256 threads, thread t owns k=t.
template <int TL>
__global__ __launch_bounds__(256) void score_softmax(const float* __restrict__ qp,
                                                     const float* __restrict__ kpT,
                                                     const int* __restrict__ mask,
                                                     const float* __restrict__ w3,
                                                     float* __restrict__ out) {
    const int t    = threadIdx.x;            // k
    const int row0 = blockIdx.x * TL;        // global q-row
    const int b    = row0 >> 8;              // LQ=256 rows per batch

    const float* kpb = kpT + (size_t)b * A * LK;
    const float* qpr = qp + (size_t)row0 * A;

    float acc[TL];
#pragma unroll
    for (int j = 0; j < TL; ++j) acc[j] = 0.f;

#pragma unroll 8
    for (int a = 0; a < A; ++a) {
        float kv = kpb[a * LK + t];          // coalesced, L1/L2-resident
        float w  = w3[a];                    // uniform -> s_load
#pragma unroll
        for (int j = 0; j < TL; ++j) {
            float s  = qpr[j * A + a] + kv;  // qpr uniform -> s_load
            float e  = __builtin_amdgcn_exp2f(s * TWO_LOG2E);   // e^(2s)
            float r  = __builtin_amdgcn_rcpf(1.0f + e);
            float th = fmaf(-2.0f, r, 1.0f); // tanh(s)
            acc[j]   = fmaf(th, w, acc[j]);
        }
    }

    // mask
    const int* mrow = mask + (size_t)row0 * LK;
    float sc[TL];
#pragma unroll
    for (int j = 0; j < TL; ++j) {
        int m = mrow[j * LK + t];
        sc[j] = (m == 0) ? NEG_INF : acc[j];
    }

    // block softmax over 256 threads (4 waves)
    __shared__ float red[TL][8];
    const int wave = t >> 6, lane = t & 63;

#pragma unroll
    for (int j = 0; j < TL; ++j) {
        float m = sc[j];
#pragma unroll
        for (int off = 32; off > 0; off >>= 1)
            m = fmaxf(m, __shfl_xor(m, off));
        if (lane == 0) red[j][wave] = m;
    }
    __syncthreads();
    float rowmax[TL];
#pragma unroll
    for (int j = 0; j < TL; ++j)
        rowmax[j] = fmaxf(fmaxf(red[j][0], red[j][1]), fmaxf(red[j][2], red[j][3]));
    __syncthreads();

    float p[TL];
#pragma unroll
    for (int j = 0; j < TL; ++j)
        p[j] = __builtin_amdgcn_exp2f((sc[j] - rowmax[j]) * LOG2E);

#pragma unroll
    for (int j = 0; j < TL; ++j) {
        float s = p[j];
#pragma unroll
        for (int off = 32; off > 0; off >>= 1)
            s += __shfl_xor(s, off);
        if (lane == 0) red[j][wave] = s;
    }
    __syncthreads();
#pragma unroll
    for (int j = 0; j < TL; ++j) {
        float rowsum = (red[j][0] + red[j][1]) + (red[j][2] + red[j][3]);
        out[(size_t)(row0 + j) * LK + t] = p[j] * __builtin_amdgcn_rcpf(rowsum);
    }
}

extern "C" void kernel_launch(void* const* d_in, const int* in_sizes, int n_in,
                              void* d_out, int out_size, void* d_ws, size_t ws_size,
                              hipStream_t stream) {
    const float* Q    = (const float*)d_in[0];   // [B,LQ,1,D]
    const float* K    = (const float*)d_in[1];   // [B,1,LK,D]
    const int*   mask = (const int*)d_in[2];     // [B,LQ,LK]
    const float* W1   = (const float*)d_in[3];   // [A,D]
    const float* W2   = (const float*)d_in[4];   // [A,D]
    const float* w3   = (const float*)d_in[5];   // [A]
    float* out = (float*)d_out;

    float* ws  = (float*)d_ws;
    float* W1T = ws;                 // D*A
    float* W2T = W1T + (size_t)D * A;
    float* qp  = W2T + (size_t)D * A;        // [B*LQ][A]
    float* kpT = qp + (size_t)B * LQ * A;    // [B][A][LK]

    dim3 tb(32, 8);
    transpose_w<<<dim3(16, 8), tb, 0, stream>>>(W1, W1T);
    transpose_w<<<dim3(16, 8), tb, 0, stream>>>(W2, W2T);

    proj_kernel<8><<<(B * LQ) / 8, 256, 0, stream>>>(Q, W1T, qp, 0);
    proj_kernel<8><<<(B * LK) / 8, 256, 0, stream>>>(K, W2T, kpT, 1);

    score_softmax<4><<<(B * LQ) / 4, 256, 0, stream>>>(qp, kpT, mask, w3, out);
}

// Round 2
// 65.630 us; speedup vs baseline: 2.0117x; 2.0117x over previous
//
#include <hip/hip_runtime.h>
#include <hip/hip_bf16.h>
#include <cstdint>

// Problem dims (fixed by reference)
constexpr int B  = 8;
constexpr int LQ = 256;
constexpr int LK = 256;
constexpr int D  = 512;   // Dq == Dk
constexpr int A  = 256;

constexpr float NEG_INF   = -1e15f;               // matches reference -INFINITY
constexpr float LOG2E     = 1.4426950408889634f;
constexpr float TWO_LOG2E = 2.8853900817779268f;  // folded into W at staging

// GEMM tiling
constexpr int BR = 32;   // rows per block (q/k rows)
constexpr int BC = 64;   // cols per block (a)
constexpr int BK = 64;   // k-chunk
constexpr int XS_STRIDE = 34;  // [BK][BR] pad -> even stride keeps b64 align, breaks bank aliasing
constexpr int WS_STRIDE = 68;  // [BK][BC] pad -> keeps 16B align for b128 reads

// ---------------------------------------------------------------------------
// Combined projection GEMM:
//   rows 0..2047   : qp'[row][a]  = (Q[row] . W1[a]) * TWO_LOG2E
//   rows 2048..4095: kp'[b][a][k] = (K[row] . W2[a]) * TWO_LOG2E  (transposed out)
// W is read in its native [A][D] layout and transposed into LDS during staging.
// ---------------------------------------------------------------------------
__global__ __launch_bounds__(256) void proj_gemm(const float* __restrict__ Q,
                                                 const float* __restrict__ Kin,
                                                 const float* __restrict__ W1,
                                                 const float* __restrict__ W2,
                                                 float* __restrict__ qp,
                                                 float* __restrict__ kp) {
    __shared__ float Xs[BK][XS_STRIDE];  // [k][r]  (transposed X tile)
    __shared__ float Ws[BK][WS_STRIDE];  // [k][c]  (transposed W tile, pre-scaled)

    const int t       = threadIdx.x;
    const int tile_c  = blockIdx.x & 3;        // 4 col tiles (A=256 / BC=64)
    const int tile_r  = blockIdx.x >> 2;       // 128 row tiles
    const int rowbase = tile_r * BR;           // 0..4064
    const bool isQ    = rowbase < 2048;

    const float* X = isQ ? (Q   + (size_t)rowbase * D)
                         : (Kin + (size_t)(rowbase - 2048) * D);
    const float* W = (isQ ? W1 : W2) + (size_t)(tile_c * BC) * D;

    // staging maps (coalesced global reads)
    const int sx_r = t >> 3;            // 0..31 (row within X tile)
    const int sx_k = (t & 7) * 8;       // 0..56 (k offset, 8 floats per thread)
    const int sw_c = t >> 2;            // 0..63 (a within W tile)
    const int sw_k = (t & 3) * 16;      // 0,16,32,48 (16 floats per thread)

    // compute maps: thread owns 2 rows x 4 cols
    const int cg = t & 15, rg = t >> 4;
    const int c0 = cg * 4, r0 = rg * 2;

    float acc[2][4] = {};

    for (int k0 = 0; k0 < D; k0 += BK) {
        // issue global loads early
        const float* xptr = X + (size_t)sx_r * D + k0 + sx_k;
        float4 xa = *(const float4*)(xptr);
        float4 xb = *(const float4*)(xptr + 4);
        const float* wptr = W + (size_t)sw_c * D + k0 + sw_k;
        float4 wv0 = *(const float4*)(wptr);
        float4 wv1 = *(const float4*)(wptr + 4);
        float4 wv2 = *(const float4*)(wptr + 8);
        float4 wv3 = *(const float4*)(wptr + 12);

        __syncthreads();  // previous chunk's compute done before overwrite

        Xs[sx_k + 0][sx_r] = xa.x;
        Xs[sx_k + 1][sx_r] = xa.y;
        Xs[sx_k + 2][sx_r] = xa.z;
        Xs[sx_k + 3][sx_r] = xa.w;
        Xs[sx_k + 4][sx_r] = xb.x;
        Xs[sx_k + 5][sx_r] = xb.y;
        Xs[sx_k + 6][sx_r] = xb.z;
        Xs[sx_k + 7][sx_r] = xb.w;

        Ws[sw_k +  0][sw_c] = wv0.x * TWO_LOG2E;
        Ws[sw_k +  1][sw_c] = wv0.y * TWO_LOG2E;
        Ws[sw_k +  2][sw_c] = wv0.z * TWO_LOG2E;
        Ws[sw_k +  3][sw_c] = wv0.w * TWO_LOG2E;
        Ws[sw_k +  4][sw_c] = wv1.x * TWO_LOG2E;
        Ws[sw_k +  5][sw_c] = wv1.y * TWO_LOG2E;
        Ws[sw_k +  6][sw_c] = wv1.z * TWO_LOG2E;
        Ws[sw_k +  7][sw_c] = wv1.w * TWO_LOG2E;
        Ws[sw_k +  8][sw_c] = wv2.x * TWO_LOG2E;
        Ws[sw_k +  9][sw_c] = wv2.y * TWO_LOG2E;
        Ws[sw_k + 10][sw_c] = wv2.z * TWO_LOG2E;
        Ws[sw_k + 11][sw_c] = wv2.w * TWO_LOG2E;
        Ws[sw_k + 12][sw_c] = wv3.x * TWO_LOG2E;
        Ws[sw_k + 13][sw_c] = wv3.y * TWO_LOG2E;
        Ws[sw_k + 14][sw_c] = wv3.z * TWO_LOG2E;
        Ws[sw_k + 15][sw_c] = wv3.w * TWO_LOG2E;

        __syncthreads();

#pragma unroll 8
        for (int kk = 0; kk < BK; ++kk) {
            float2 xr = *(const float2*)&Xs[kk][r0];
            float4 wr = *(const float4*)&Ws[kk][c0];
            acc[0][0] = fmaf(xr.x, wr.x, acc[0][0]);
            acc[0][1] = fmaf(xr.x, wr.y, acc[0][1]);
            acc[0][2] = fmaf(xr.x, wr.z, acc[0][2]);
            acc[0][3] = fmaf(xr.x, wr.w, acc[0][3]);
            acc[1][0] = fmaf(xr.y, wr.x, acc[1][0]);
            acc[1][1] = fmaf(xr.y, wr.y, acc[1][1]);
            acc[1][2] = fmaf(xr.y, wr.z, acc[1][2]);
            acc[1][3] = fmaf(xr.y, wr.w, acc[1][3]);
        }
    }

    const int cbase = tile_c * BC;
    if (isQ) {
#pragma unroll
        for (int i = 0; i < 2; ++i) {
            float4 v = make_float4(acc[i][0], acc[i][1], acc[i][2], acc[i][3]);
            *(float4*)(qp + (size_t)(rowbase + r0 + i) * A + cbase + c0) = v;
        }
    } else {
        // transpose 32x64 tile through LDS, write kp[b][a][k] coalesced along k
        __syncthreads();
        float* T = &Xs[0][0];  // reuse: need [BC][XS_STRIDE] = 64*34 <= 64*34 ok
#pragma unroll
        for (int i = 0; i < 2; ++i)
#pragma unroll
            for (int j = 0; j < 4; ++j)
                T[(c0 + j) * XS_STRIDE + (r0 + i)] = acc[i][j];
        __syncthreads();

        const int bb    = (rowbase - 2048) >> 8;
        const int kbase = rowbase & 255;
        const int kk    = t & 31;        // k within tile
        const int ag    = t >> 5;        // 0..7
        float* dst = kp + (size_t)bb * A * LK + (size_t)cbase * LK + kbase;
#pragma unroll
        for (int j = 0; j < 8; ++j) {
            int a2 = ag + 8 * j;         // 0..63
            dst[(size_t)a2 * LK + kk] = T[a2 * XS_STRIDE + kk];
        }
    }
}

// ---------------------------------------------------------------------------
// Fused score + mask + softmax.
// score'[q][k] = sum_a (-2*w3[a]) * 1/(1 + 2^(qp'[q][a]+kp'[a][k]))
// (differs from reference score by the row-constant +sum(w3): softmax-invariant)
// ---------------------------------------------------------------------------
template <int TL>
__global__ __launch_bounds__(256) void score_softmax(const float* __restrict__ qp,
                                                     const float* __restrict__ kpT,
                                                     const int* __restrict__ mask,
                                                     const float* __restrict__ w3,
                                                     float* __restrict__ out) {
    const int t    = threadIdx.x;            // k
    const int row0 = blockIdx.x * TL;        // global q-row
    const int b    = row0 >> 8;              // LQ=256 rows per batch

    const float* kpb = kpT + (size_t)b * A * LK;
    const float* qpr = qp + (size_t)row0 * A;

    float acc[TL];
#pragma unroll
    for (int j = 0; j < TL; ++j) acc[j] = 0.f;

#pragma unroll 8
    for (int a = 0; a < A; ++a) {
        float kv = kpb[a * LK + t];          // coalesced, L2-resident
        float wv = -2.0f * w3[a];            // uniform -> scalar
#pragma unroll
        for (int j = 0; j < TL; ++j) {
            float u = qpr[j * A + a] + kv;                    // = 2*log2e*s
            float e = __builtin_amdgcn_exp2f(u);              // e^(2s)
            float r = __builtin_amdgcn_rcpf(1.0f + e);
            acc[j]  = fmaf(r, wv, acc[j]);                    // score' accum
        }
    }

    // mask
    const int* mrow = mask + (size_t)row0 * LK;
    float sc[TL];
#pragma unroll
    for (int j = 0; j < TL; ++j) {
        int m = mrow[j * LK + t];
        sc[j] = (m == 0) ? NEG_INF : acc[j];
    }

    // block softmax over 256 threads (4 waves)
    __shared__ float red[TL][8];
    const int wave = t >> 6, lane = t & 63;

#pragma unroll
    for (int j = 0; j < TL; ++j) {
        float m = sc[j];
#pragma unroll
        for (int off = 32; off > 0; off >>= 1)
            m = fmaxf(m, __shfl_xor(m, off));
        if (lane == 0) red[j][wave] = m;
    }
    __syncthreads();
    float rowmax[TL];
#pragma unroll
    for (int j = 0; j < TL; ++j)
        rowmax[j] = fmaxf(fmaxf(red[j][0], red[j][1]), fmaxf(red[j][2], red[j][3]));
    __syncthreads();

    float p[TL];
#pragma unroll
    for (int j = 0; j < TL; ++j)
        p[j] = __builtin_amdgcn_exp2f((sc[j] - rowmax[j]) * LOG2E);

#pragma unroll
    for (int j = 0; j < TL; ++j) {
        float s = p[j];
#pragma unroll
        for (int off = 32; off > 0; off >>= 1)
            s += __shfl_xor(s, off);
        if (lane == 0) red[j][wave] = s;
    }
    __syncthreads();
#pragma unroll
    for (int j = 0; j < TL; ++j) {
        float rowsum = (red[j][0] + red[j][1]) + (red[j][2] + red[j][3]);
        out[(size_t)(row0 + j) * LK + t] = p[j] * __builtin_amdgcn_rcpf(rowsum);
    }
}

extern "C" void kernel_launch(void* const* d_in, const int* in_sizes, int n_in,
                              void* d_out, int out_size, void* d_ws, size_t ws_size,
                              hipStream_t stream) {
    const float* Q    = (const float*)d_in[0];   // [B,LQ,1,D]
    const float* K    = (const float*)d_in[1];   // [B,1,LK,D]
    const int*   mask = (const int*)d_in[2];     // [B,LQ,LK]
    const float* W1   = (const float*)d_in[3];   // [A,D]
    const float* W2   = (const float*)d_in[4];   // [A,D]
    const float* w3   = (const float*)d_in[5];   // [A]
    float* out = (float*)d_out;

    float* ws  = (float*)d_ws;
    float* qp  = ws;                          // [B*LQ][A]   (pre-scaled by 2*log2e)
    float* kpT = qp + (size_t)B * LQ * A;     // [B][A][LK]  (pre-scaled)

    proj_gemm<<<512, 256, 0, stream>>>(Q, K, W1, W2, qp, kpT);
    score_softmax<4><<<512, 256, 0, stream>>>(qp, kpT, mask, w3, out);
}

// Round 3
// 62.485 us; speedup vs baseline: 2.1129x; 1.0503x over previous
//
#include <hip/hip_runtime.h>
#include <hip/hip_bf16.h>
#include <cstdint>

// Problem dims (fixed by reference)
constexpr int B  = 8;
constexpr int LQ = 256;
constexpr int LK = 256;
constexpr int D  = 512;   // Dq == Dk
constexpr int A  = 256;

constexpr float NEG_INF   = -1e15f;               // matches reference -INFINITY
constexpr float LOG2E     = 1.4426950408889634f;
constexpr float TWO_LOG2E = 2.8853900817779268f;  // folded into W at staging

// GEMM tiling
constexpr int BR = 32;   // rows per block (q/k rows)
constexpr int BC = 64;   // cols per block (a)
constexpr int BK = 64;   // k-chunk
constexpr int XS_STRIDE = 34;
constexpr int WS_STRIDE = 68;

// flat layout: [ qp (B*LQ*A) | kp (B*A*LK) ]
constexpr int QP_ELEMS = B * LQ * A;              // 524288
constexpr int NELEM    = QP_ELEMS + B * A * LK;   // 1048576

// ---------------------------------------------------------------------------
// Split-K projection GEMM (K-half per block). Partials:
//   part[kh] rows 0..2047   : qp'[row][a]  = (Q[row] . W1[a]) * TWO_LOG2E
//   part[kh] rows 2048..4095: kp'[b][a][k] = (K[row] . W2[a]) * TWO_LOG2E
// ---------------------------------------------------------------------------
__global__ __launch_bounds__(256) void proj_gemm(const float* __restrict__ Q,
                                                 const float* __restrict__ Kin,
                                                 const float* __restrict__ W1,
                                                 const float* __restrict__ W2,
                                                 float* __restrict__ part) {
    __shared__ float Xs[BK][XS_STRIDE];  // [k][r]
    __shared__ float Ws[BK][WS_STRIDE];  // [k][c] pre-scaled

    const int t       = threadIdx.x;
    const int kh      = blockIdx.x >> 9;       // 0..1 (split-K half)
    const int tile    = blockIdx.x & 511;
    const int tile_c  = tile & 3;              // 4 col tiles
    const int tile_r  = tile >> 2;             // 128 row tiles
    const int rowbase = tile_r * BR;
    const bool isQ    = rowbase < 2048;

    const float* X = isQ ? (Q   + (size_t)rowbase * D)
                         : (Kin + (size_t)(rowbase - 2048) * D);
    const float* W = (isQ ? W1 : W2) + (size_t)(tile_c * BC) * D;
    float* out = part + (size_t)kh * NELEM;

    const int sx_r = t >> 3;            // 0..31
    const int sx_k = (t & 7) * 8;       // 8 floats per thread
    const int sw_c = t >> 2;            // 0..63
    const int sw_k = (t & 3) * 16;      // 16 floats per thread

    const int cg = t & 15, rg = t >> 4;
    const int c0 = cg * 4, r0 = rg * 2;

    float acc[2][4] = {};

    const int kbeg = kh * 256, kend = kbeg + 256;
    for (int k0 = kbeg; k0 < kend; k0 += BK) {
        const float* xptr = X + (size_t)sx_r * D + k0 + sx_k;
        float4 xa = *(const float4*)(xptr);
        float4 xb = *(const float4*)(xptr + 4);
        const float* wptr = W + (size_t)sw_c * D + k0 + sw_k;
        float4 wv0 = *(const float4*)(wptr);
        float4 wv1 = *(const float4*)(wptr + 4);
        float4 wv2 = *(const float4*)(wptr + 8);
        float4 wv3 = *(const float4*)(wptr + 12);

        __syncthreads();

        Xs[sx_k + 0][sx_r] = xa.x;
        Xs[sx_k + 1][sx_r] = xa.y;
        Xs[sx_k + 2][sx_r] = xa.z;
        Xs[sx_k + 3][sx_r] = xa.w;
        Xs[sx_k + 4][sx_r] = xb.x;
        Xs[sx_k + 5][sx_r] = xb.y;
        Xs[sx_k + 6][sx_r] = xb.z;
        Xs[sx_k + 7][sx_r] = xb.w;

        Ws[sw_k +  0][sw_c] = wv0.x * TWO_LOG2E;
        Ws[sw_k +  1][sw_c] = wv0.y * TWO_LOG2E;
        Ws[sw_k +  2][sw_c] = wv0.z * TWO_LOG2E;
        Ws[sw_k +  3][sw_c] = wv0.w * TWO_LOG2E;
        Ws[sw_k +  4][sw_c] = wv1.x * TWO_LOG2E;
        Ws[sw_k +  5][sw_c] = wv1.y * TWO_LOG2E;
        Ws[sw_k +  6][sw_c] = wv1.z * TWO_LOG2E;
        Ws[sw_k +  7][sw_c] = wv1.w * TWO_LOG2E;
        Ws[sw_k +  8][sw_c] = wv2.x * TWO_LOG2E;
        Ws[sw_k +  9][sw_c] = wv2.y * TWO_LOG2E;
        Ws[sw_k + 10][sw_c] = wv2.z * TWO_LOG2E;
        Ws[sw_k + 11][sw_c] = wv2.w * TWO_LOG2E;
        Ws[sw_k + 12][sw_c] = wv3.x * TWO_LOG2E;
        Ws[sw_k + 13][sw_c] = wv3.y * TWO_LOG2E;
        Ws[sw_k + 14][sw_c] = wv3.z * TWO_LOG2E;
        Ws[sw_k + 15][sw_c] = wv3.w * TWO_LOG2E;

        __syncthreads();

#pragma unroll 8
        for (int kk = 0; kk < BK; ++kk) {
            float2 xr = *(const float2*)&Xs[kk][r0];
            float4 wr = *(const float4*)&Ws[kk][c0];
            acc[0][0] = fmaf(xr.x, wr.x, acc[0][0]);
            acc[0][1] = fmaf(xr.x, wr.y, acc[0][1]);
            acc[0][2] = fmaf(xr.x, wr.z, acc[0][2]);
            acc[0][3] = fmaf(xr.x, wr.w, acc[0][3]);
            acc[1][0] = fmaf(xr.y, wr.x, acc[1][0]);
            acc[1][1] = fmaf(xr.y, wr.y, acc[1][1]);
            acc[1][2] = fmaf(xr.y, wr.z, acc[1][2]);
            acc[1][3] = fmaf(xr.y, wr.w, acc[1][3]);
        }
    }

    const int cbase = tile_c * BC;
    if (isQ) {
#pragma unroll
        for (int i = 0; i < 2; ++i) {
            float4 v = make_float4(acc[i][0], acc[i][1], acc[i][2], acc[i][3]);
            *(float4*)(out + (size_t)(rowbase + r0 + i) * A + cbase + c0) = v;
        }
    } else {
        // transpose 32x64 tile through LDS, write kp[b][a][k] coalesced along k
        __syncthreads();
        float* T = &Xs[0][0];  // 64*34 floats, exactly Xs capacity
#pragma unroll
        for (int i = 0; i < 2; ++i)
#pragma unroll
            for (int j = 0; j < 4; ++j)
                T[(c0 + j) * XS_STRIDE + (r0 + i)] = acc[i][j];
        __syncthreads();

        const int bb    = (rowbase - 2048) >> 8;
        const int kbase = rowbase & 255;
        const int kk    = t & 31;
        const int ag    = t >> 5;
        float* dst = out + QP_ELEMS + (size_t)bb * A * LK + (size_t)cbase * LK + kbase;
#pragma unroll
        for (int j = 0; j < 8; ++j) {
            int a2 = ag + 8 * j;
            dst[(size_t)a2 * LK + kk] = T[a2 * XS_STRIDE + kk];
        }
    }
}

// ---------------------------------------------------------------------------
// reduce: fin[i] = part0[i] + part1[i], 1M floats as float4
// ---------------------------------------------------------------------------
__global__ __launch_bounds__(256) void reduce2(const float* __restrict__ part,
                                               float* __restrict__ fin) {
    int i = blockIdx.x * 256 + threadIdx.x;       // 262144 float4s
    const float4* p0 = (const float4*)part;
    const float4* p1 = (const float4*)(part + NELEM);
    float4 a = p0[i], b = p1[i];
    ((float4*)fin)[i] = make_float4(a.x + b.x, a.y + b.y, a.z + b.z, a.w + b.w);
}

// ---------------------------------------------------------------------------
// Fused score + mask + softmax. 2 q-rows per block; shared-rcp across the pair.
// score'[q][k] = -2 * sum_a w3[a] / (1 + 2^(qp'[q][a]+kp'[a][k]))
// (row-constant sum(w3) dropped: softmax-invariant)
// ---------------------------------------------------------------------------
__global__ __launch_bounds__(256) void score_softmax(const float* __restrict__ qp,
                                                     const float* __restrict__ kpT,
                                                     const int* __restrict__ mask,
                                                     const float* __restrict__ w3,
                                                     float* __restrict__ out) {
    const int t    = threadIdx.x;            // k
    const int row0 = blockIdx.x * 2;         // global q-row
    const int b    = row0 >> 8;

    const float* kpb = kpT + (size_t)b * A * LK;
    const float* q0  = qp + (size_t)row0 * A;

    float acc0 = 0.f, acc1 = 0.f;

#pragma unroll 8
    for (int a = 0; a < A; ++a) {
        float kv = kpb[a * LK + t];          // coalesced, L2-resident
        float w  = w3[a];                    // uniform -> s_load
        float u0 = q0[a] + kv;               // q0[..] uniform -> s_load
        float u1 = q0[A + a] + kv;
        float e0 = __builtin_amdgcn_exp2f(u0);
        float e1 = __builtin_amdgcn_exp2f(u1);
        float a0 = 1.0f + e0;
        float a1 = 1.0f + e1;
        float rp = __builtin_amdgcn_rcpf(a0 * a1);  // one rcp per 2 elements
        acc0 = fmaf(a1 * rp, w, acc0);
        acc1 = fmaf(a0 * rp, w, acc1);
    }

    // mask + the -2 scale (applied once, preserves softmax ordering)
    const int* mrow = mask + (size_t)row0 * LK;
    float sc0 = (mrow[t]      == 0) ? NEG_INF : -2.0f * acc0;
    float sc1 = (mrow[LK + t] == 0) ? NEG_INF : -2.0f * acc1;

    // block softmax over 256 threads (4 waves), 2 rows
    __shared__ float red[2][8];
    const int wave = t >> 6, lane = t & 63;

    float m0 = sc0, m1 = sc1;
#pragma unroll
    for (int off = 32; off > 0; off >>= 1) {
        m0 = fmaxf(m0, __shfl_xor(m0, off));
        m1 = fmaxf(m1, __shfl_xor(m1, off));
    }
    if (lane == 0) { red[0][wave] = m0; red[1][wave] = m1; }
    __syncthreads();
    float rmax0 = fmaxf(fmaxf(red[0][0], red[0][1]), fmaxf(red[0][2], red[0][3]));
    float rmax1 = fmaxf(fmaxf(red[1][0], red[1][1]), fmaxf(red[1][2], red[1][3]));
    __syncthreads();

    float p0 = __builtin_amdgcn_exp2f((sc0 - rmax0) * LOG2E);
    float p1 = __builtin_amdgcn_exp2f((sc1 - rmax1) * LOG2E);

    float s0 = p0, s1 = p1;
#pragma unroll
    for (int off = 32; off > 0; off >>= 1) {
        s0 += __shfl_xor(s0, off);
        s1 += __shfl_xor(s1, off);
    }
    if (lane == 0) { red[0][wave] = s0; red[1][wave] = s1; }
    __syncthreads();
    float sum0 = (red[0][0] + red[0][1]) + (red[0][2] + red[0][3]);
    float sum1 = (red[1][0] + red[1][1]) + (red[1][2] + red[1][3]);

    out[(size_t)row0 * LK + t]       = p0 * __builtin_amdgcn_rcpf(sum0);
    out[(size_t)(row0 + 1) * LK + t] = p1 * __builtin_amdgcn_rcpf(sum1);
}

extern "C" void kernel_launch(void* const* d_in, const int* in_sizes, int n_in,
                              void* d_out, int out_size, void* d_ws, size_t ws_size,
                              hipStream_t stream) {
    const float* Q    = (const float*)d_in[0];   // [B,LQ,1,D]
    const float* K    = (const float*)d_in[1];   // [B,1,LK,D]
    const int*   mask = (const int*)d_in[2];     // [B,LQ,LK]
    const float* W1   = (const float*)d_in[3];   // [A,D]
    const float* W2   = (const float*)d_in[4];   // [A,D]
    const float* w3   = (const float*)d_in[5];   // [A]
    float* out = (float*)d_out;

    float* ws   = (float*)d_ws;
    float* fin  = ws;                    // [NELEM]  qp | kp
    float* part = ws + NELEM;            // [2][NELEM]
    float* qp   = fin;
    float* kpT  = fin + QP_ELEMS;

    proj_gemm<<<1024, 256, 0, stream>>>(Q, K, W1, W2, part);
    reduce2<<<NELEM / 4 / 256, 256, 0, stream>>>(part, fin);
    score_softmax<<<(B * LQ) / 2, 256, 0, stream>>>(qp, kpT, mask, w3, out);
}

// Round 6
// 59.025 us; speedup vs baseline: 2.2368x; 1.0586x over previous
//
#include <hip/hip_runtime.h>
#include <hip/hip_bf16.h>
#include <cstdint>

// Problem dims (fixed by reference)
constexpr int B  = 8;
constexpr int LQ = 256;
constexpr int LK = 256;
constexpr int D  = 512;   // Dq == Dk
constexpr int A  = 256;

constexpr float NEG_INF   = -1e15f;               // matches reference -INFINITY
constexpr float LOG2E     = 1.4426950408889634f;
constexpr float TWO_LOG2E = 2.8853900817779268f;  // folded into W at staging

// GEMM tiling
constexpr int BR = 32;   // rows per block (q/k rows)
constexpr int BC = 64;   // cols per block (a)
constexpr int BK = 64;   // k-chunk
constexpr int XS_STRIDE = 34;
constexpr int WS_STRIDE = 68;

constexpr int QP_ELEMS = B * LQ * A;              // 524288

// ---------------------------------------------------------------------------
// Combined projection GEMM — EXACT round-2 structure (post-timing proven):
// loads issued at loop top, then barrier, stage, barrier, compute.
//   rows 0..2047   : qp'[row][a]  = (Q[row] . W1[a]) * TWO_LOG2E
//   rows 2048..4095: kp'[b][a][k] = (K[row] . W2[a]) * TWO_LOG2E  (transposed)
// ---------------------------------------------------------------------------
__global__ __launch_bounds__(256) void proj_gemm(const float* __restrict__ Q,
                                                 const float* __restrict__ Kin,
                                                 const float* __restrict__ W1,
                                                 const float* __restrict__ W2,
                                                 float* __restrict__ qp,
                                                 float* __restrict__ kp) {
    __shared__ float Xs[BK][XS_STRIDE];  // [k][r]  (transposed X tile)
    __shared__ float Ws[BK][WS_STRIDE];  // [k][c]  (transposed W tile, pre-scaled)

    const int t       = threadIdx.x;
    const int tile_c  = blockIdx.x & 3;        // 4 col tiles (A=256 / BC=64)
    const int tile_r  = blockIdx.x >> 2;       // 128 row tiles
    const int rowbase = tile_r * BR;           // 0..4064
    const bool isQ    = rowbase < 2048;

    const float* X = isQ ? (Q   + (size_t)rowbase * D)
                         : (Kin + (size_t)(rowbase - 2048) * D);
    const float* W = (isQ ? W1 : W2) + (size_t)(tile_c * BC) * D;

    // staging maps (coalesced global reads)
    const int sx_r = t >> 3;            // 0..31 (row within X tile)
    const int sx_k = (t & 7) * 8;       // 0..56 (k offset, 8 floats per thread)
    const int sw_c = t >> 2;            // 0..63 (a within W tile)
    const int sw_k = (t & 3) * 16;      // 0,16,32,48 (16 floats per thread)

    // compute maps: thread owns 2 rows x 4 cols
    const int cg = t & 15, rg = t >> 4;
    const int c0 = cg * 4, r0 = rg * 2;

    float acc[2][4] = {};

    for (int k0 = 0; k0 < D; k0 += BK) {
        // issue global loads early
        const float* xptr = X + (size_t)sx_r * D + k0 + sx_k;
        float4 xa = *(const float4*)(xptr);
        float4 xb = *(const float4*)(xptr + 4);
        const float* wptr = W + (size_t)sw_c * D + k0 + sw_k;
        float4 wv0 = *(const float4*)(wptr);
        float4 wv1 = *(const float4*)(wptr + 4);
        float4 wv2 = *(const float4*)(wptr + 8);
        float4 wv3 = *(const float4*)(wptr + 12);

        __syncthreads();  // previous chunk's compute done before overwrite

        Xs[sx_k + 0][sx_r] = xa.x;
        Xs[sx_k + 1][sx_r] = xa.y;
        Xs[sx_k + 2][sx_r] = xa.z;
        Xs[sx_k + 3][sx_r] = xa.w;
        Xs[sx_k + 4][sx_r] = xb.x;
        Xs[sx_k + 5][sx_r] = xb.y;
        Xs[sx_k + 6][sx_r] = xb.z;
        Xs[sx_k + 7][sx_r] = xb.w;

        Ws[sw_k +  0][sw_c] = wv0.x * TWO_LOG2E;
        Ws[sw_k +  1][sw_c] = wv0.y * TWO_LOG2E;
        Ws[sw_k +  2][sw_c] = wv0.z * TWO_LOG2E;
        Ws[sw_k +  3][sw_c] = wv0.w * TWO_LOG2E;
        Ws[sw_k +  4][sw_c] = wv1.x * TWO_LOG2E;
        Ws[sw_k +  5][sw_c] = wv1.y * TWO_LOG2E;
        Ws[sw_k +  6][sw_c] = wv1.z * TWO_LOG2E;
        Ws[sw_k +  7][sw_c] = wv1.w * TWO_LOG2E;
        Ws[sw_k +  8][sw_c] = wv2.x * TWO_LOG2E;
        Ws[sw_k +  9][sw_c] = wv2.y * TWO_LOG2E;
        Ws[sw_k + 10][sw_c] = wv2.z * TWO_LOG2E;
        Ws[sw_k + 11][sw_c] = wv2.w * TWO_LOG2E;
        Ws[sw_k + 12][sw_c] = wv3.x * TWO_LOG2E;
        Ws[sw_k + 13][sw_c] = wv3.y * TWO_LOG2E;
        Ws[sw_k + 14][sw_c] = wv3.z * TWO_LOG2E;
        Ws[sw_k + 15][sw_c] = wv3.w * TWO_LOG2E;

        __syncthreads();

#pragma unroll 8
        for (int kk = 0; kk < BK; ++kk) {
            float2 xr = *(const float2*)&Xs[kk][r0];
            float4 wr = *(const float4*)&Ws[kk][c0];
            acc[0][0] = fmaf(xr.x, wr.x, acc[0][0]);
            acc[0][1] = fmaf(xr.x, wr.y, acc[0][1]);
            acc[0][2] = fmaf(xr.x, wr.z, acc[0][2]);
            acc[0][3] = fmaf(xr.x, wr.w, acc[0][3]);
            acc[1][0] = fmaf(xr.y, wr.x, acc[1][0]);
            acc[1][1] = fmaf(xr.y, wr.y, acc[1][1]);
            acc[1][2] = fmaf(xr.y, wr.z, acc[1][2]);
            acc[1][3] = fmaf(xr.y, wr.w, acc[1][3]);
        }
    }

    const int cbase = tile_c * BC;
    if (isQ) {
#pragma unroll
        for (int i = 0; i < 2; ++i) {
            float4 v = make_float4(acc[i][0], acc[i][1], acc[i][2], acc[i][3]);
            *(float4*)(qp + (size_t)(rowbase + r0 + i) * A + cbase + c0) = v;
        }
    } else {
        // transpose 32x64 tile through LDS, write kp[b][a][k] coalesced along k
        __syncthreads();
        float* T = &Xs[0][0];  // 64*34 floats, exactly Xs capacity
#pragma unroll
        for (int i = 0; i < 2; ++i)
#pragma unroll
            for (int j = 0; j < 4; ++j)
                T[(c0 + j) * XS_STRIDE + (r0 + i)] = acc[i][j];
        __syncthreads();

        const int bb    = (rowbase - 2048) >> 8;
        const int kbase = rowbase & 255;
        const int kk    = t & 31;
        const int ag    = t >> 5;
        float* dst = kp + (size_t)bb * A * LK + (size_t)cbase * LK + kbase;
#pragma unroll
        for (int j = 0; j < 8; ++j) {
            int a2 = ag + 8 * j;
            dst[(size_t)a2 * LK + kk] = T[a2 * XS_STRIDE + kk];
        }
    }
}

// ---------------------------------------------------------------------------
// Fused score + mask + softmax — EXACT round-3 structure (post-timing proven):
// 2 q-rows per block; shared-rcp across the pair.
// score'[q][k] = -2 * sum_a w3[a] / (1 + 2^(qp'[q][a]+kp'[a][k]))
// (row-constant sum(w3) dropped: softmax-invariant)
// ---------------------------------------------------------------------------
__global__ __launch_bounds__(256) void score_softmax(const float* __restrict__ qp,
                                                     const float* __restrict__ kpT,
                                                     const int* __restrict__ mask,
                                                     const float* __restrict__ w3,
                                                     float* __restrict__ out) {
    const int t    = threadIdx.x;            // k
    const int row0 = blockIdx.x * 2;         // global q-row
    const int b    = row0 >> 8;

    const float* kpb = kpT + (size_t)b * A * LK;
    const float* q0  = qp + (size_t)row0 * A;

    float acc0 = 0.f, acc1 = 0.f;

#pragma unroll 8
    for (int a = 0; a < A; ++a) {
        float kv = kpb[a * LK + t];          // coalesced, L2-resident
        float w  = w3[a];                    // uniform -> s_load
        float u0 = q0[a] + kv;               // q0[..] uniform -> s_load
        float u1 = q0[A + a] + kv;
        float e0 = __builtin_amdgcn_exp2f(u0);
        float e1 = __builtin_amdgcn_exp2f(u1);
        float a0 = 1.0f + e0;
        float a1 = 1.0f + e1;
        float rp = __builtin_amdgcn_rcpf(a0 * a1);  // one rcp per 2 elements
        acc0 = fmaf(a1 * rp, w, acc0);
        acc1 = fmaf(a0 * rp, w, acc1);
    }

    // mask + the -2 scale (applied once, preserves softmax ordering)
    const int* mrow = mask + (size_t)row0 * LK;
    float sc0 = (mrow[t]      == 0) ? NEG_INF : -2.0f * acc0;
    float sc1 = (mrow[LK + t] == 0) ? NEG_INF : -2.0f * acc1;

    // block softmax over 256 threads (4 waves), 2 rows
    __shared__ float red[2][8];
    const int wave = t >> 6, lane = t & 63;

    float m0 = sc0, m1 = sc1;
#pragma unroll
    for (int off = 32; off > 0; off >>= 1) {
        m0 = fmaxf(m0, __shfl_xor(m0, off));
        m1 = fmaxf(m1, __shfl_xor(m1, off));
    }
    if (lane == 0) { red[0][wave] = m0; red[1][wave] = m1; }
    __syncthreads();
    float rmax0 = fmaxf(fmaxf(red[0][0], red[0][1]), fmaxf(red[0][2], red[0][3]));
    float rmax1 = fmaxf(fmaxf(red[1][0], red[1][1]), fmaxf(red[1][2], red[1][3]));
    __syncthreads();

    float p0 = __builtin_amdgcn_exp2f((sc0 - rmax0) * LOG2E);
    float p1 = __builtin_amdgcn_exp2f((sc1 - rmax1) * LOG2E);

    float s0 = p0, s1 = p1;
#pragma unroll
    for (int off = 32; off > 0; off >>= 1) {
        s0 += __shfl_xor(s0, off);
        s1 += __shfl_xor(s1, off);
    }
    if (lane == 0) { red[0][wave] = s0; red[1][wave] = s1; }
    __syncthreads();
    float sum0 = (red[0][0] + red[0][1]) + (red[0][2] + red[0][3]);
    float sum1 = (red[1][0] + red[1][1]) + (red[1][2] + red[1][3]);

    out[(size_t)row0 * LK + t]       = p0 * __builtin_amdgcn_rcpf(sum0);
    out[(size_t)(row0 + 1) * LK + t] = p1 * __builtin_amdgcn_rcpf(sum1);
}

extern "C" void kernel_launch(void* const* d_in, const int* in_sizes, int n_in,
                              void* d_out, int out_size, void* d_ws, size_t ws_size,
                              hipStream_t stream) {
    const float* Q    = (const float*)d_in[0];   // [B,LQ,1,D]
    const float* K    = (const float*)d_in[1];   // [B,1,LK,D]
    const int*   mask = (const int*)d_in[2];     // [B,LQ,LK]
    const float* W1   = (const float*)d_in[3];   // [A,D]
    const float* W2   = (const float*)d_in[4];   // [A,D]
    const float* w3   = (const float*)d_in[5];   // [A]
    float* out = (float*)d_out;

    float* ws  = (float*)d_ws;
    float* qp  = ws;                     // [B*LQ][A]   (pre-scaled by 2*log2e)
    float* kpT = ws + QP_ELEMS;          // [B][A][LK]  (pre-scaled)

    proj_gemm<<<512, 256, 0, stream>>>(Q, K, W1, W2, qp, kpT);
    score_softmax<<<(B * LQ) / 2, 256, 0, stream>>>(qp, kpT, mask, w3, out);
}